// Round 11
// baseline (192.989 us; speedup 1.0000x reference)
//
#include <hip/hip_runtime.h>

#define NNODES 100000
#define NEDGES 600000
#define NCLASS 26
#define HID    128

#define SHIFT  9
#define BCOLS  512                    // cols per bucket
#define NBKT   196                    // ceil(100000/512)
#define EPB    1024                   // edges per partition block
#define NBE    586                    // ceil(600000/1024)
#define NH     (NBKT * NBE)           // 114856 histogram cells

typedef __attribute__((ext_vector_type(8))) _Float16 f16x8;
typedef __attribute__((ext_vector_type(4))) float f32x4;

__device__ inline unsigned short f2h(float f) {   // RNE fp32->fp16
    union { _Float16 h; unsigned short s; } c;
    c.h = (_Float16)f;
    return c.s;
}
__device__ inline unsigned int packh(float a, float b) {
    return (unsigned int)f2h(a) | ((unsigned int)f2h(b) << 16);
}
__device__ inline float hlo(unsigned int p) {
    union { unsigned short s; _Float16 h; } c;
    c.s = (unsigned short)p;
    return (float)c.h;
}
__device__ inline float hhi(unsigned int p) {
    union { unsigned short s; _Float16 h; } c;
    c.s = (unsigned short)(p >> 16);
    return (float)c.h;
}

// 16 biased-uint8 decode+FMAs from a 16B fragment.
// Stored byte = q+128; true contribution v*(b-128) handled by caller via vsum.
__device__ inline void fma16_u8(float* acc, float v, uint4 g) {
    unsigned int u[4] = { g.x, g.y, g.z, g.w };
#pragma unroll
    for (int w = 0; w < 4; w++) {
        acc[w * 4 + 0] = fmaf(v, (float)( u[w]        & 0xffu), acc[w * 4 + 0]);
        acc[w * 4 + 1] = fmaf(v, (float)((u[w] >> 8 ) & 0xffu), acc[w * 4 + 1]);
        acc[w * 4 + 2] = fmaf(v, (float)((u[w] >> 16) & 0xffu), acc[w * 4 + 2]);
        acc[w * 4 + 3] = fmaf(v, (float)( u[w] >> 24        ), acc[w * 4 + 3]);
    }
}

// ---- pass A: per-block LDS histogram of edge->bucket; extra blocks past NBE
// do the weight transposes (absorbed from the old prep_k). ----
__global__ __launch_bounds__(256) void histA_k(const int* __restrict__ col,
                                               int* __restrict__ H,
                                               const float* __restrict__ W2,
                                               const float* __restrict__ W1,
                                               const float* __restrict__ Wfc,
                                               unsigned short* __restrict__ wt,
                                               unsigned short* __restrict__ w1t,
                                               unsigned short* __restrict__ wfct) {
    int t = threadIdx.x;
    if (blockIdx.x >= NBE) {              // weight-transpose blocks
        int b = blockIdx.x - NBE;
        if (b < 64) {
            int idx = b * 256 + t;
            int c = idx >> 7, k = idx & 127;
            wt[c * 128 + k] = f2h(W2[k * 128 + c]);
        } else if (b < 80) {
            int idx = (b - 64) * 256 + t;
            int c = idx >> 5, k = idx & 31;
            w1t[c * 32 + k] = (k < NCLASS) ? f2h(W1[k * 128 + c]) : (unsigned short)0;
        } else {
            int idx = (b - 80) * 256 + t;
            int c = idx >> 7, k = idx & 127;
            wfct[c * 128 + k] = (c < NCLASS) ? f2h(Wfc[k * NCLASS + c]) : (unsigned short)0;
        }
        return;
    }
    __shared__ int h[NBKT];
    for (int i = t; i < NBKT; i += 256) h[i] = 0;
    __syncthreads();
    int base = blockIdx.x * EPB;
#pragma unroll
    for (int u = 0; u < 4; u++) {
        int e = base + t + u * 256;
        if (e < NEDGES) atomicAdd(&h[col[e] >> SHIFT], 1);
    }
    __syncthreads();
    for (int i = t; i < NBKT; i += 256) H[i * NBE + blockIdx.x] = h[i];
}

__global__ void scanH1_k(const int* __restrict__ in, int* __restrict__ incl,
                         int* __restrict__ aux, int n) {
    __shared__ int s[256];
    int t = threadIdx.x, gi = blockIdx.x * 256 + t;
    s[t] = (gi < n) ? in[gi] : 0;
    __syncthreads();
    for (int off = 1; off < 256; off <<= 1) {
        int x = (t >= off) ? s[t - off] : 0;
        __syncthreads();
        s[t] += x;
        __syncthreads();
    }
    if (gi < n) incl[gi] = s[t];
    if (t == 255) aux[blockIdx.x] = s[255];
}

__global__ void scan2_k(int* __restrict__ aux, int n) {  // 1 block, 512 thr
    __shared__ int s[512];
    int t = threadIdx.x;
    s[t] = (t < n) ? aux[t] : 0;
    __syncthreads();
    for (int off = 1; off < 512; off <<= 1) {
        int x = (t >= off) ? s[t - off] : 0;
        __syncthreads();
        s[t] += x;
        __syncthreads();
    }
    if (t < n) aux[t] = s[t];
}

// exclusive offset of cell gi, reconstructed from incl/H/aux
__device__ inline int exoff(const int* __restrict__ incl, const int* __restrict__ H,
                            const int* __restrict__ aux, int gi) {
    int add = (gi >= 256) ? aux[(gi >> 8) - 1] : 0;
    return incl[gi] - H[gi] + add;
}

// ---- pass B: partition edges into bucket-contiguous storage ----
__global__ __launch_bounds__(256) void partB_k(const int* __restrict__ row,
                                               const int* __restrict__ col,
                                               const float* __restrict__ w,
                                               const int* __restrict__ incl,
                                               const int* __restrict__ H,
                                               const int* __restrict__ aux,
                                               uint2* __restrict__ rw,
                                               unsigned short* __restrict__ lc) {
    __shared__ int off[NBKT];
    __shared__ int cur[NBKT];
    int t = threadIdx.x;
    for (int i = t; i < NBKT; i += 256) {
        off[i] = exoff(incl, H, aux, i * NBE + blockIdx.x);
        cur[i] = 0;
    }
    __syncthreads();
    int base = blockIdx.x * EPB;
#pragma unroll
    for (int u = 0; u < 4; u++) {
        int e = base + t + u * 256;
        if (e < NEDGES) {
            int c = col[e], b = c >> SHIFT;
            int p = off[b] + atomicAdd(&cur[b], 1);
            rw[p] = make_uint2((unsigned int)row[e], __float_as_uint(w[e]));
            lc[p] = (unsigned short)(c & (BCOLS - 1));
        }
    }
}

// ---- fused per-bucket: degree/wsum -> dis + rowptr -> meta -> int8 xq (absorbed
// from prep_k: this block owns nodes c0..c0+ncols and has ws[] in LDS). ----
__global__ __launch_bounds__(256) void segbp_k(const uint2* __restrict__ rw,
                                               const unsigned short* __restrict__ lc,
                                               const int* __restrict__ incl,
                                               const int* __restrict__ H,
                                               const int* __restrict__ aux,
                                               const float* __restrict__ x,
                                               int* __restrict__ rowptr,
                                               float* __restrict__ dis,
                                               uint2* __restrict__ meta,
                                               unsigned int* __restrict__ xq,
                                               float* __restrict__ xscale) {
    __shared__ int   cnt[BCOLS];
    __shared__ float ws[BCOLS];
    __shared__ int   rpl[BCOLS];
    __shared__ int   ps[256];
    int b = blockIdx.x, t = threadIdx.x;
    int c0 = b << SHIFT;
    int ncols = min(BCOLS, NNODES - c0);
    for (int i = t; i < BCOLS; i += 256) { cnt[i] = 0; ws[i] = 0.f; }
    __syncthreads();
    int s    = exoff(incl, H, aux, b * NBE);
    int eend = (b == NBKT - 1) ? NEDGES : exoff(incl, H, aux, (b + 1) * NBE);
    for (int e = s + t; e < eend; e += 256) {
        uint2 m = rw[e];
        int l = lc[e];
        atomicAdd(&cnt[l], 1);
        atomicAdd(&ws[l], __uint_as_float(m.y));
    }
    __syncthreads();
    for (int i = t; i < ncols; i += 256) dis[c0 + i] = rsqrtf(1.0f + ws[i]);
    int a0 = cnt[2 * t], a1 = cnt[2 * t + 1];
    ps[t] = a0 + a1;
    __syncthreads();
    for (int off = 1; off < 256; off <<= 1) {
        int x2 = (t >= off) ? ps[t - off] : 0;
        __syncthreads();
        ps[t] += x2;
        __syncthreads();
    }
    int ex = (t > 0) ? ps[t - 1] : 0;
    rpl[2 * t]     = s + ex;
    rpl[2 * t + 1] = s + ex + a0;
    if (2 * t     < ncols) rowptr[c0 + 2 * t]     = s + ex;
    if (2 * t + 1 < ncols) rowptr[c0 + 2 * t + 1] = s + ex + a0;
    if (b == NBKT - 1 && t == 0) rowptr[NNODES] = NEDGES;
    cnt[2 * t] = 0; cnt[2 * t + 1] = 0;   // reuse as cursors
    __syncthreads();
    for (int e = s + t; e < eend; e += 256) {
        uint2 m = rw[e];
        int l = lc[e];
        int pos = rpl[l] + atomicAdd(&cnt[l], 1);
        meta[pos] = make_uint2(m.x, m.y);   // (src, w)
    }
    // ---- absorbed prep: per-row int8 quantize of dis*x for this bucket's nodes.
    // 8 lanes per node; ws[] still valid (cnt was reused, ws was not).
    for (int pass = 0; pass < 16; pass++) {
        int i = pass * 32 + (t >> 3);       // node index within bucket (uniform per 8-lane group)
        int l = t & 7;
        if (i < ncols) {
            int r = c0 + i;
            float d = rsqrtf(1.0f + ws[i]);
            float v[4]; float m = 0.f;
#pragma unroll
            for (int k = 0; k < 4; k++) {
                int f = l * 4 + k;
                v[k] = (f < NCLASS) ? d * x[(size_t)r * NCLASS + f] : 0.f;
                m = fmaxf(m, fabsf(v[k]));
            }
#pragma unroll
            for (int sft = 1; sft < 8; sft <<= 1)
                m = fmaxf(m, __shfl_xor(m, sft));
            float inv = (m > 0.f) ? 127.f / m : 0.f;
            unsigned int q = 0;
#pragma unroll
            for (int k = 0; k < 4; k++) {
                int qq = (int)rintf(v[k] * inv) + 128;
                q |= ((unsigned int)qq & 0xffu) << (8 * k);
            }
            xq[(size_t)r * 8 + l] = q;
            if (l == 0) xscale[r] = m * (1.f / 127.f);
        }
    }
}

// ---- agg 26-dim, 8 lanes/node, biased-int8 gather (32B rows, 3.2MB L2-fit) ----
__global__ __launch_bounds__(256) void agg26_k(const int* __restrict__ rowptr,
                                               const uint2* __restrict__ meta,
                                               const unsigned int* __restrict__ xq,
                                               const float* __restrict__ xscale,
                                               const float* __restrict__ dis,
                                               unsigned int* __restrict__ aggx) {
    int node = blockIdx.x * 32 + (threadIdx.x >> 3);   // N divisible by 32
    int l8 = threadIdx.x & 7;

    float vs = xscale[node];                 // self term, weight 1
    float vsum = vs;
    unsigned int s = xq[(size_t)node * 8 + l8];
    float acc[4];
    acc[0] = vs * (float)( s        & 0xffu);
    acc[1] = vs * (float)((s >> 8 ) & 0xffu);
    acc[2] = vs * (float)((s >> 16) & 0xffu);
    acc[3] = vs * (float)( s >> 24        );
    int j = rowptr[node], jend = rowptr[node + 1];
    for (; j < jend; j++) {
        uint2 m = meta[j];
        float v = __uint_as_float(m.y) * xscale[m.x];
        unsigned int g = xq[(size_t)m.x * 8 + l8];
        vsum += v;
        acc[0] = fmaf(v, (float)( g        & 0xffu), acc[0]);
        acc[1] = fmaf(v, (float)((g >> 8 ) & 0xffu), acc[1]);
        acc[2] = fmaf(v, (float)((g >> 16) & 0xffu), acc[2]);
        acc[3] = fmaf(v, (float)( g >> 24        ), acc[3]);
    }
    float b128 = 128.f * vsum;
    float d = dis[node];
    ((uint2*)aggx)[(size_t)node * 8 + l8] =
        make_uint2(packh(d * (acc[0] - b128), d * (acc[1] - b128)),
                   packh(d * (acc[2] - b128), d * (acc[3] - b128)));
}

// ---- fused gemm1+gemm2, 64-row tile, Ws-STAGED, wave-private h1s (fp16 MFMA) ----
// Epilogue: per-row max -> symmetric int8 (biased) into hB8 + hscale.
__global__ __launch_bounds__(256) void gemm12_k(const unsigned short* __restrict__ aggx,
                                                const unsigned short* __restrict__ w1t,
                                                const float* __restrict__ b1,
                                                const unsigned short* __restrict__ wt,
                                                const float* __restrict__ dis,
                                                unsigned char* __restrict__ C8,
                                                float* __restrict__ hscale, int N) {
    __shared__ unsigned short h1s[64 * 136];   // 17408 B, wave-private rows
    __shared__ unsigned short Ws[128 * 72];    // 18432 B, W2^T K-chunk (64)
    const int tid  = threadIdx.x;
    const int wv = tid >> 6, lane = tid & 63;
    const int quad = lane >> 4, l16 = lane & 15;
    const int row0 = blockIdx.x * 64;
    const int wrow = wv * 16;

    // stage Ws chunk c=0 (K 0..63)
#pragma unroll
    for (int jj = 0; jj < 4; jj++) {
        int idx = tid + jj * 256;
        int r = idx >> 3, ku = idx & 7;
        *(uint4*)&Ws[r * 72 + ku * 8] = *(const uint4*)&wt[(size_t)r * 128 + ku * 8];
    }

    // ---- phase 1: wave's 16 rows of h1 = relu(aggx @ W1 + b1) into its LDS rows ----
    {
        int ar = row0 + wrow + l16;
        f16x8 af1 = (ar < N) ? *(const f16x8*)&aggx[(size_t)ar * 32 + quad * 8]
                             : (f16x8)(_Float16)0.f;
#pragma unroll
        for (int n = 0; n < 8; n++) {
            f16x8 bw = *(const f16x8*)&w1t[(n * 16 + l16) * 32 + quad * 8];
            f32x4 hacc = __builtin_amdgcn_mfma_f32_16x16x32_f16(af1, bw, (f32x4)0.f, 0, 0, 0);
            int col = n * 16 + l16;
            float bv = b1[col];
#pragma unroll
            for (int r = 0; r < 4; r++)
                h1s[(wrow + quad * 4 + r) * 136 + col] = f2h(fmaxf(hacc[r] + bv, 0.f));
        }
    }
    __syncthreads();   // Ws c=0 visible (h1s rows are wave-private)

    // ---- phase 2: wave's 16 rows @ W2, K in two staged chunks ----
    f16x8 af[4];
#pragma unroll
    for (int kc = 0; kc < 4; kc++)
        af[kc] = *(const f16x8*)&h1s[(wrow + l16) * 136 + kc * 32 + quad * 8];

    f32x4 acc[8];
#pragma unroll
    for (int n = 0; n < 8; n++) acc[n] = (f32x4)0.f;

    for (int c = 0; c < 2; c++) {
        if (c == 1) {
            __syncthreads();
#pragma unroll
            for (int jj = 0; jj < 4; jj++) {
                int idx = tid + jj * 256;
                int r = idx >> 3, ku = idx & 7;
                *(uint4*)&Ws[r * 72 + ku * 8] =
                    *(const uint4*)&wt[(size_t)r * 128 + 64 + ku * 8];
            }
            __syncthreads();
        }
#pragma unroll
        for (int n = 0; n < 8; n++) {
#pragma unroll
            for (int kc = 0; kc < 2; kc++) {
                f16x8 bfr = *(const f16x8*)&Ws[(n * 16 + l16) * 72 + kc * 32 + quad * 8];
                acc[n] = __builtin_amdgcn_mfma_f32_16x16x32_f16(
                    af[c * 2 + kc], bfr, acc[n], 0, 0, 0);
            }
        }
    }

    // ---- epilogue: t2s values, per-row max, int8 quantize ----
    const int rbase = row0 + wrow + quad * 4;
    float dv[4];
#pragma unroll
    for (int r = 0; r < 4; r++)
        dv[r] = (rbase + r < N) ? dis[rbase + r] : 0.f;

    float vv[8][4];
    float rmax[4] = { 0.f, 0.f, 0.f, 0.f };
#pragma unroll
    for (int n = 0; n < 8; n++)
#pragma unroll
        for (int r = 0; r < 4; r++) {
            vv[n][r] = dv[r] * acc[n][r];
            rmax[r] = fmaxf(rmax[r], fabsf(vv[n][r]));
        }
    // reduce across the 16-lane quad group (lane bits 0..3)
#pragma unroll
    for (int s = 1; s < 16; s <<= 1) {
#pragma unroll
        for (int r = 0; r < 4; r++)
            rmax[r] = fmaxf(rmax[r], __shfl_xor(rmax[r], s));
    }
    float inv[4];
#pragma unroll
    for (int r = 0; r < 4; r++)
        inv[r] = (rmax[r] > 0.f) ? 127.f / rmax[r] : 0.f;
    if (l16 == 0) {
#pragma unroll
        for (int r = 0; r < 4; r++)
            if (rbase + r < N) hscale[rbase + r] = rmax[r] * (1.f / 127.f);
    }
#pragma unroll
    for (int n = 0; n < 8; n++) {
        int col = n * 16 + l16;
#pragma unroll
        for (int r = 0; r < 4; r++) {
            if (rbase + r < N) {
                int q = (int)rintf(vv[n][r] * inv[r]);
                C8[(size_t)(rbase + r) * 128 + col] = (unsigned char)(q + 128);
            }
        }
    }
}

// ---- fused agg128 + fc: 8 lanes/node, biased-int8 gather.
// value = scale[src]*(byte-128); bias folded via vsum. ----
__global__ __launch_bounds__(256) void aggfc_k(const int* __restrict__ rowptr,
                                               const uint2* __restrict__ meta,
                                               const uint4* __restrict__ h8,
                                               const float* __restrict__ hscale,
                                               const float* __restrict__ dis,
                                               const float* __restrict__ b2,
                                               const unsigned short* __restrict__ wfct,
                                               const float* __restrict__ bfc,
                                               float* __restrict__ out, int N) {
    __shared__ unsigned short h2s[64 * 136];
    const int tid = threadIdx.x;
    const int wv = tid >> 6, lane = tid & 63;
    const int grp = lane >> 3, l8 = lane & 7;   // 8 groups x 8 lanes
    const int nbase = blockIdx.x * 64;

    // ---- gather phase: wave wv fills rows wv*16 .. wv*16+15 ----
    for (int p = 0; p < 2; p++) {
        int r = wv * 16 + p * 8 + grp;
        int node = nbase + r;
        float acc[16];
#pragma unroll
        for (int k = 0; k < 16; k++) acc[k] = 0.f;
        float d = 0.f;
        if (node < N) {
            d = dis[node];
            float vs = hscale[node];           // self term, weight 1
            float vsum = vs;
            uint4 s0 = h8[(size_t)node * 8 + l8];
            fma16_u8(acc, vs, s0);
            int j = rowptr[node], jend = rowptr[node + 1];
            for (; j < jend; j++) {
                uint2 m = meta[j];
                float v = __uint_as_float(m.y) * hscale[m.x];
                uint4 g = h8[(size_t)m.x * 8 + l8];
                vsum += v;
                fma16_u8(acc, v, g);
            }
            float b128 = 128.f * vsum;
#pragma unroll
            for (int k = 0; k < 16; k++) acc[k] -= b128;
        }
        // bias + relu + scale; lane covers cols l8*16 .. l8*16+15
        unsigned int wpk[8];
#pragma unroll
        for (int q = 0; q < 4; q++) {
            float4 bv = ((const float4*)b2)[l8 * 4 + q];
            float a0 = fmaxf(fmaf(d, acc[q * 4 + 0], bv.x), 0.f);
            float a1 = fmaxf(fmaf(d, acc[q * 4 + 1], bv.y), 0.f);
            float a2 = fmaxf(fmaf(d, acc[q * 4 + 2], bv.z), 0.f);
            float a3 = fmaxf(fmaf(d, acc[q * 4 + 3], bv.w), 0.f);
            if (node >= N) { a0 = a1 = a2 = a3 = 0.f; }
            wpk[q * 2]     = packh(a0, a1);
            wpk[q * 2 + 1] = packh(a2, a3);
        }
        *(uint4*)&h2s[r * 136 + l8 * 16] =
            make_uint4(wpk[0], wpk[1], wpk[2], wpk[3]);
        *(uint4*)&h2s[r * 136 + l8 * 16 + 8] =
            make_uint4(wpk[4], wpk[5], wpk[6], wpk[7]);
    }
    // no __syncthreads(): each wave reads back only the rows it wrote

    // ---- fc phase: wave wv handles its rows wv*16..+15 ----
    const int q = lane >> 4, m = lane & 15;
    f16x8 af[4];
#pragma unroll
    for (int ks = 0; ks < 4; ks++)
        af[ks] = *(const f16x8*)&h2s[(wv * 16 + m) * 136 + ks * 32 + q * 8];

#pragma unroll
    for (int n = 0; n < 2; n++) {
        f32x4 o = (f32x4)0.f;
#pragma unroll
        for (int ks = 0; ks < 4; ks++) {
            f16x8 bfr = *(const f16x8*)&wfct[(size_t)(n * 16 + m) * 128 + ks * 32 + q * 8];
            o = __builtin_amdgcn_mfma_f32_16x16x32_f16(af[ks], bfr, o, 0, 0, 0);
        }
        int col = n * 16 + m;
        if (col < NCLASS) {
            float bv = bfc[col];
            int r0 = nbase + wv * 16 + q * 4;
#pragma unroll
            for (int r = 0; r < 4; r++) {
                if (r0 + r < N)
                    out[(size_t)(r0 + r) * NCLASS + col] = o[r] + bv;
            }
        }
    }
}

extern "C" void kernel_launch(void* const* d_in, const int* in_sizes, int n_in,
                              void* d_out, int out_size, void* d_ws, size_t ws_size,
                              hipStream_t stream) {
    const float* x   = (const float*)d_in[0];
    const int*   ei  = (const int*)d_in[1];
    const float* ew  = (const float*)d_in[2];
    const float* W1  = (const float*)d_in[3];
    const float* b1  = (const float*)d_in[4];
    const float* W2  = (const float*)d_in[5];
    const float* b2  = (const float*)d_in[6];
    const float* Wfc = (const float*)d_in[7];
    const float* bfc = (const float*)d_in[8];
    float* out = (float*)d_out;

    const int N = NNODES;
    const int* erow = ei;
    const int* ecol = ei + NEDGES;

    // ws layout (float-unit offsets):
    float* fws    = (float*)d_ws;
    float* dis    = fws;                                       // 100000
    int*   rowptr = (int*)(fws + 100000);                      // 100001 (+pad)
    int*   H      = (int*)(fws + 200004);                      // 114856
    int*   incl   = (int*)(fws + 314860);                      // 114856
    int*   aux    = (int*)(fws + 429716);                      // 512
    uint2* rw     = (uint2*)(fws + 430228);                    // 600000 uint2
    unsigned short* lc = (unsigned short*)(fws + 1630228);     // 600000 u16
    uint2* meta   = (uint2*)(fws + 1930228);                   // 600000 uint2
    unsigned short* wt16   = (unsigned short*)(fws + 3130228); // 128*128
    unsigned short* w1t16  = (unsigned short*)(fws + 3138420); // 128*32
    unsigned short* wfct16 = (unsigned short*)(fws + 3140468); // 32*128
    unsigned int*   xq     = (unsigned int*)(fws + 3142516);   // N*8 uints (int8 xs)
    float*          xscale = (float*)(fws + 3942516);          // N per-row scales
    unsigned int*   aggx   = (unsigned int*)(fws + 4742516);   // N*16 (fp16 agg)
    unsigned char*  hB8    = (unsigned char*)(fws + 6342516);  // N*128 u8 (biased int8)
    float*          hscale = (float*)(fws + 9542516);          // N per-row scales

    const int gScan = (NH + 255) / 256;   // 449
    const int gA26  = N / 32;             // 3125
    const int g64   = (N + 63) / 64;      // 1563

    // ---- CSR build (4 kernels; histA carries the weight transposes) ----
    histA_k<<<NBE + 96, 256, 0, stream>>>(ecol, H, W2, W1, Wfc, wt16, w1t16, wfct16);
    scanH1_k<<<gScan, 256, 0, stream>>>(H, incl, aux, NH);
    scan2_k<<<1, 512, 0, stream>>>(aux, gScan);
    partB_k<<<NBE, 256, 0, stream>>>(erow, ecol, ew, incl, H, aux, rw, lc);
    segbp_k<<<NBKT, 256, 0, stream>>>(rw, lc, incl, H, aux, x, rowptr, dis, meta,
                                      xq, xscale);

    // ---- layer 1 agg (int8 gather, L2-resident) -> fused gemm1+gemm2 ----
    agg26_k<<<gA26, 256, 0, stream>>>(rowptr, meta, xq, xscale, dis, aggx);
    gemm12_k<<<g64, 256, 0, stream>>>((const unsigned short*)aggx, w1t16, b1,
                                      wt16, dis, hB8, hscale, N);

    // ---- fused agg128 + fc (biased-int8 gather) ----
    aggfc_k<<<g64, 256, 0, stream>>>(rowptr, meta, (const uint4*)hB8, hscale, dis, b2,
                                     wfct16, bfc, out, N);
}

// Round 13
// 182.076 us; speedup vs baseline: 1.0599x; 1.0599x over previous
//
#include <hip/hip_runtime.h>

#define NNODES 100000
#define NEDGES 600000
#define NCLASS 26
#define HID    128

#define SHIFT  9
#define BCOLS  512                    // cols per bucket
#define NBKT   196                    // ceil(100000/512)
#define EPB    1024                   // edges per partition block
#define NBE    586                    // ceil(600000/1024)
#define NH     (NBKT * NBE)           // 114856 histogram cells

typedef __attribute__((ext_vector_type(8))) _Float16 f16x8;
typedef __attribute__((ext_vector_type(4))) float f32x4;

__device__ inline unsigned short f2h(float f) {   // RNE fp32->fp16
    union { _Float16 h; unsigned short s; } c;
    c.h = (_Float16)f;
    return c.s;
}
__device__ inline unsigned int packh(float a, float b) {
    return (unsigned int)f2h(a) | ((unsigned int)f2h(b) << 16);
}
__device__ inline float hlo(unsigned int p) {
    union { unsigned short s; _Float16 h; } c;
    c.s = (unsigned short)p;
    return (float)c.h;
}
__device__ inline float hhi(unsigned int p) {
    union { unsigned short s; _Float16 h; } c;
    c.s = (unsigned short)(p >> 16);
    return (float)c.h;
}

// 16 biased-uint8 decode+FMAs from a 16B fragment.
// Stored byte = q+128; true contribution v*(b-128) handled by caller via vsum.
__device__ inline void fma16_u8(float* acc, float v, uint4 g) {
    unsigned int u[4] = { g.x, g.y, g.z, g.w };
#pragma unroll
    for (int w = 0; w < 4; w++) {
        acc[w * 4 + 0] = fmaf(v, (float)( u[w]        & 0xffu), acc[w * 4 + 0]);
        acc[w * 4 + 1] = fmaf(v, (float)((u[w] >> 8 ) & 0xffu), acc[w * 4 + 1]);
        acc[w * 4 + 2] = fmaf(v, (float)((u[w] >> 16) & 0xffu), acc[w * 4 + 2]);
        acc[w * 4 + 3] = fmaf(v, (float)( u[w] >> 24        ), acc[w * 4 + 3]);
    }
}

// ---- pass A: per-block LDS histogram of edge->bucket ----
__global__ __launch_bounds__(256) void histA_k(const int* __restrict__ col,
                                               int* __restrict__ H) {
    __shared__ int h[NBKT];
    int t = threadIdx.x;
    for (int i = t; i < NBKT; i += 256) h[i] = 0;
    __syncthreads();
    int base = blockIdx.x * EPB;
#pragma unroll
    for (int u = 0; u < 4; u++) {
        int e = base + t + u * 256;
        if (e < NEDGES) atomicAdd(&h[col[e] >> SHIFT], 1);
    }
    __syncthreads();
    for (int i = t; i < NBKT; i += 256) H[i * NBE + blockIdx.x] = h[i];
}

__global__ void scanH1_k(const int* __restrict__ in, int* __restrict__ incl,
                         int* __restrict__ aux, int n) {
    __shared__ int s[256];
    int t = threadIdx.x, gi = blockIdx.x * 256 + t;
    s[t] = (gi < n) ? in[gi] : 0;
    __syncthreads();
    for (int off = 1; off < 256; off <<= 1) {
        int x = (t >= off) ? s[t - off] : 0;
        __syncthreads();
        s[t] += x;
        __syncthreads();
    }
    if (gi < n) incl[gi] = s[t];
    if (t == 255) aux[blockIdx.x] = s[255];
}

__global__ void scan2_k(int* __restrict__ aux, int n) {  // 1 block, 512 thr
    __shared__ int s[512];
    int t = threadIdx.x;
    s[t] = (t < n) ? aux[t] : 0;
    __syncthreads();
    for (int off = 1; off < 512; off <<= 1) {
        int x = (t >= off) ? s[t - off] : 0;
        __syncthreads();
        s[t] += x;
        __syncthreads();
    }
    if (t < n) aux[t] = s[t];
}

// exclusive offset of cell gi, reconstructed from incl/H/aux
__device__ inline int exoff(const int* __restrict__ incl, const int* __restrict__ H,
                            const int* __restrict__ aux, int gi) {
    int add = (gi >= 256) ? aux[(gi >> 8) - 1] : 0;
    return incl[gi] - H[gi] + add;
}

// ---- pass B: partition edges into bucket-contiguous storage ----
__global__ __launch_bounds__(256) void partB_k(const int* __restrict__ row,
                                               const int* __restrict__ col,
                                               const float* __restrict__ w,
                                               const int* __restrict__ incl,
                                               const int* __restrict__ H,
                                               const int* __restrict__ aux,
                                               uint2* __restrict__ rw,
                                               unsigned short* __restrict__ lc) {
    __shared__ int off[NBKT];
    __shared__ int cur[NBKT];
    int t = threadIdx.x;
    for (int i = t; i < NBKT; i += 256) {
        off[i] = exoff(incl, H, aux, i * NBE + blockIdx.x);
        cur[i] = 0;
    }
    __syncthreads();
    int base = blockIdx.x * EPB;
#pragma unroll
    for (int u = 0; u < 4; u++) {
        int e = base + t + u * 256;
        if (e < NEDGES) {
            int c = col[e], b = c >> SHIFT;
            int p = off[b] + atomicAdd(&cur[b], 1);
            rw[p] = make_uint2((unsigned int)row[e], __float_as_uint(w[e]));
            lc[p] = (unsigned short)(c & (BCOLS - 1));
        }
    }
}

// ---- fused per-bucket: degree/wsum -> dis + rowptr (LDS scan) -> place meta ----
__global__ __launch_bounds__(256) void segbp_k(const uint2* __restrict__ rw,
                                               const unsigned short* __restrict__ lc,
                                               const int* __restrict__ incl,
                                               const int* __restrict__ H,
                                               const int* __restrict__ aux,
                                               int* __restrict__ rowptr,
                                               float* __restrict__ dis,
                                               uint2* __restrict__ meta) {
    __shared__ int   cnt[BCOLS];
    __shared__ float ws[BCOLS];
    __shared__ int   rpl[BCOLS];
    __shared__ int   ps[256];
    int b = blockIdx.x, t = threadIdx.x;
    int c0 = b << SHIFT;
    int ncols = min(BCOLS, NNODES - c0);
    for (int i = t; i < BCOLS; i += 256) { cnt[i] = 0; ws[i] = 0.f; }
    __syncthreads();
    int s    = exoff(incl, H, aux, b * NBE);
    int eend = (b == NBKT - 1) ? NEDGES : exoff(incl, H, aux, (b + 1) * NBE);
    for (int e = s + t; e < eend; e += 256) {
        uint2 m = rw[e];
        int l = lc[e];
        atomicAdd(&cnt[l], 1);
        atomicAdd(&ws[l], __uint_as_float(m.y));
    }
    __syncthreads();
    for (int i = t; i < ncols; i += 256) dis[c0 + i] = rsqrtf(1.0f + ws[i]);
    int a0 = cnt[2 * t], a1 = cnt[2 * t + 1];
    ps[t] = a0 + a1;
    __syncthreads();
    for (int off = 1; off < 256; off <<= 1) {
        int x = (t >= off) ? ps[t - off] : 0;
        __syncthreads();
        ps[t] += x;
        __syncthreads();
    }
    int ex = (t > 0) ? ps[t - 1] : 0;
    rpl[2 * t]     = s + ex;
    rpl[2 * t + 1] = s + ex + a0;
    if (2 * t     < ncols) rowptr[c0 + 2 * t]     = s + ex;
    if (2 * t + 1 < ncols) rowptr[c0 + 2 * t + 1] = s + ex + a0;
    if (b == NBKT - 1 && t == 0) rowptr[NNODES] = NEDGES;
    cnt[2 * t] = 0; cnt[2 * t + 1] = 0;   // reuse as cursors
    __syncthreads();
    for (int e = s + t; e < eend; e += 256) {
        uint2 m = rw[e];
        int l = lc[e];
        int pos = rpl[l] + atomicAdd(&cnt[l], 1);
        meta[pos] = make_uint2(m.x, m.y);   // (src, w)
    }
}

// ---- fused prep: W2^T f16 | W1^T padded f16 | Wfc^T padded f16 |
// xq = per-row int8 of dis*x (biased) + xscale ----
__global__ __launch_bounds__(256) void prep_k(const float* __restrict__ W2,
                                              const float* __restrict__ W1,
                                              const float* __restrict__ Wfc,
                                              const float* __restrict__ x,
                                              const float* __restrict__ dis,
                                              unsigned short* __restrict__ wt,
                                              unsigned short* __restrict__ w1t,
                                              unsigned short* __restrict__ wfct,
                                              unsigned int* __restrict__ xq,
                                              float* __restrict__ xscale) {
    int b = blockIdx.x, t = threadIdx.x;
    if (b < 64) {
        int idx = b * 256 + t;
        int c = idx >> 7, k = idx & 127;
        wt[c * 128 + k] = f2h(W2[k * 128 + c]);
    } else if (b < 80) {
        int idx = (b - 64) * 256 + t;
        int c = idx >> 5, k = idx & 31;
        w1t[c * 32 + k] = (k < NCLASS) ? f2h(W1[k * 128 + c]) : (unsigned short)0;
    } else if (b < 96) {
        int idx = (b - 80) * 256 + t;
        int c = idx >> 7, k = idx & 127;
        wfct[c * 128 + k] = (c < NCLASS) ? f2h(Wfc[k * NCLASS + c]) : (unsigned short)0;
    } else {
        int idx = (b - 96) * 256 + t;
        int r = idx >> 3, l = idx & 7;
        if (r < NNODES) {
            float d = dis[r];
            float v[4]; float m = 0.f;
#pragma unroll
            for (int k = 0; k < 4; k++) {
                int f = l * 4 + k;
                v[k] = (f < NCLASS) ? d * x[r * NCLASS + f] : 0.f;
                m = fmaxf(m, fabsf(v[k]));
            }
#pragma unroll
            for (int s = 1; s < 8; s <<= 1)
                m = fmaxf(m, __shfl_xor(m, s));
            float inv = (m > 0.f) ? 127.f / m : 0.f;
            unsigned int q = 0;
#pragma unroll
            for (int k = 0; k < 4; k++) {
                int qq = (int)rintf(v[k] * inv) + 128;
                q |= ((unsigned int)qq & 0xffu) << (8 * k);
            }
            xq[(size_t)r * 8 + l] = q;
            if (l == 0) xscale[r] = m * (1.f / 127.f);
        }
    }
}

// ---- fused agg26 + gemm1 + gemm2: lane (l16=node, quad=dims quad*8..+7)
// aggregates EXACTLY its MFMA A-fragment from int8 xq (uint2 slice) -> fp16
// fragment -> relu(.@W1+b1) -> wave-private LDS -> @W2 (Ws staged) ->
// per-row int8 quantize into hB8 + hscale. Math bit-identical to the
// standalone agg26 path (same FMA order, same vsum fold, same fp16 round). ----
__global__ __launch_bounds__(256) void agggemm_k(const int* __restrict__ rowptr,
                                                 const uint2* __restrict__ meta,
                                                 const uint2* __restrict__ xq2,
                                                 const float* __restrict__ xscale,
                                                 const unsigned short* __restrict__ w1t,
                                                 const float* __restrict__ b1,
                                                 const unsigned short* __restrict__ wt,
                                                 const float* __restrict__ dis,
                                                 unsigned char* __restrict__ C8,
                                                 float* __restrict__ hscale, int N) {
    __shared__ unsigned short h1s[64 * 136];   // 17408 B, wave-private rows
    __shared__ unsigned short Ws[128 * 72];    // 18432 B, W2^T K-chunk (64)
    const int tid  = threadIdx.x;
    const int wv = tid >> 6, lane = tid & 63;
    const int quad = lane >> 4, l16 = lane & 15;
    const int row0 = blockIdx.x * 64;
    const int wrow = wv * 16;

    // stage Ws chunk c=0 (K 0..63)
#pragma unroll
    for (int jj = 0; jj < 4; jj++) {
        int idx = tid + jj * 256;
        int r = idx >> 3, ku = idx & 7;
        *(uint4*)&Ws[r * 72 + ku * 8] = *(const uint4*)&wt[(size_t)r * 128 + ku * 8];
    }

    // ---- fused layer-1 aggregation: 16 node chains per wave, int8 gather ----
    f16x8 af1 = (f16x8)(_Float16)0.f;
    {
        int ar = row0 + wrow + l16;
        if (ar < N) {
            float vs = xscale[ar];           // self term, weight 1
            float vsum = vs;
            uint2 s = xq2[(size_t)ar * 4 + quad];
            float acc[8];
            acc[0] = vs * (float)( s.x        & 0xffu);
            acc[1] = vs * (float)((s.x >> 8 ) & 0xffu);
            acc[2] = vs * (float)((s.x >> 16) & 0xffu);
            acc[3] = vs * (float)( s.x >> 24        );
            acc[4] = vs * (float)( s.y        & 0xffu);
            acc[5] = vs * (float)((s.y >> 8 ) & 0xffu);
            acc[6] = vs * (float)((s.y >> 16) & 0xffu);
            acc[7] = vs * (float)( s.y >> 24        );
            int j = rowptr[ar], jend = rowptr[ar + 1];
            for (; j < jend; j++) {
                uint2 m = meta[j];
                float v = __uint_as_float(m.y) * xscale[m.x];
                uint2 g = xq2[(size_t)m.x * 4 + quad];
                vsum += v;
                acc[0] = fmaf(v, (float)( g.x        & 0xffu), acc[0]);
                acc[1] = fmaf(v, (float)((g.x >> 8 ) & 0xffu), acc[1]);
                acc[2] = fmaf(v, (float)((g.x >> 16) & 0xffu), acc[2]);
                acc[3] = fmaf(v, (float)( g.x >> 24        ), acc[3]);
                acc[4] = fmaf(v, (float)( g.y        & 0xffu), acc[4]);
                acc[5] = fmaf(v, (float)((g.y >> 8 ) & 0xffu), acc[5]);
                acc[6] = fmaf(v, (float)((g.y >> 16) & 0xffu), acc[6]);
                acc[7] = fmaf(v, (float)( g.y >> 24        ), acc[7]);
            }
            float b128 = 128.f * vsum;
            float d = dis[ar];
#pragma unroll
            for (int k = 0; k < 8; k++)
                af1[k] = (_Float16)(d * (acc[k] - b128));
        }
    }

    // ---- phase 1: wave's 16 rows of h1 = relu(aggx @ W1 + b1) into its LDS rows ----
#pragma unroll
    for (int n = 0; n < 8; n++) {
        f16x8 bw = *(const f16x8*)&w1t[(n * 16 + l16) * 32 + quad * 8];
        f32x4 hacc = __builtin_amdgcn_mfma_f32_16x16x32_f16(af1, bw, (f32x4)0.f, 0, 0, 0);
        int col = n * 16 + l16;
        float bv = b1[col];
#pragma unroll
        for (int r = 0; r < 4; r++)
            h1s[(wrow + quad * 4 + r) * 136 + col] = f2h(fmaxf(hacc[r] + bv, 0.f));
    }
    __syncthreads();   // Ws c=0 visible (h1s rows are wave-private)

    // ---- phase 2: wave's 16 rows @ W2, K in two staged chunks ----
    f16x8 af[4];
#pragma unroll
    for (int kc = 0; kc < 4; kc++)
        af[kc] = *(const f16x8*)&h1s[(wrow + l16) * 136 + kc * 32 + quad * 8];

    f32x4 acc2[8];
#pragma unroll
    for (int n = 0; n < 8; n++) acc2[n] = (f32x4)0.f;

    for (int c = 0; c < 2; c++) {
        if (c == 1) {
            __syncthreads();
#pragma unroll
            for (int jj = 0; jj < 4; jj++) {
                int idx = tid + jj * 256;
                int r = idx >> 3, ku = idx & 7;
                *(uint4*)&Ws[r * 72 + ku * 8] =
                    *(const uint4*)&wt[(size_t)r * 128 + 64 + ku * 8];
            }
            __syncthreads();
        }
#pragma unroll
        for (int n = 0; n < 8; n++) {
#pragma unroll
            for (int kc = 0; kc < 2; kc++) {
                f16x8 bfr = *(const f16x8*)&Ws[(n * 16 + l16) * 72 + kc * 32 + quad * 8];
                acc2[n] = __builtin_amdgcn_mfma_f32_16x16x32_f16(
                    af[c * 2 + kc], bfr, acc2[n], 0, 0, 0);
            }
        }
    }

    // ---- epilogue: t2s values, per-row max, int8 quantize ----
    const int rbase = row0 + wrow + quad * 4;
    float dv[4];
#pragma unroll
    for (int r = 0; r < 4; r++)
        dv[r] = (rbase + r < N) ? dis[rbase + r] : 0.f;

    float vv[8][4];
    float rmax[4] = { 0.f, 0.f, 0.f, 0.f };
#pragma unroll
    for (int n = 0; n < 8; n++)
#pragma unroll
        for (int r = 0; r < 4; r++) {
            vv[n][r] = dv[r] * acc2[n][r];
            rmax[r] = fmaxf(rmax[r], fabsf(vv[n][r]));
        }
    // reduce across the 16-lane quad group (lane bits 0..3)
#pragma unroll
    for (int s = 1; s < 16; s <<= 1) {
#pragma unroll
        for (int r = 0; r < 4; r++)
            rmax[r] = fmaxf(rmax[r], __shfl_xor(rmax[r], s));
    }
    float inv[4];
#pragma unroll
    for (int r = 0; r < 4; r++)
        inv[r] = (rmax[r] > 0.f) ? 127.f / rmax[r] : 0.f;
    if (l16 == 0) {
#pragma unroll
        for (int r = 0; r < 4; r++)
            if (rbase + r < N) hscale[rbase + r] = rmax[r] * (1.f / 127.f);
    }
#pragma unroll
    for (int n = 0; n < 8; n++) {
        int col = n * 16 + l16;
#pragma unroll
        for (int r = 0; r < 4; r++) {
            if (rbase + r < N) {
                int q = (int)rintf(vv[n][r] * inv[r]);
                C8[(size_t)(rbase + r) * 128 + col] = (unsigned char)(q + 128);
            }
        }
    }
}

// ---- fused agg128 + fc: 8 lanes/node, biased-int8 gather.
// value = scale[src]*(byte-128); bias folded via vsum. ----
__global__ __launch_bounds__(256) void aggfc_k(const int* __restrict__ rowptr,
                                               const uint2* __restrict__ meta,
                                               const uint4* __restrict__ h8,
                                               const float* __restrict__ hscale,
                                               const float* __restrict__ dis,
                                               const float* __restrict__ b2,
                                               const unsigned short* __restrict__ wfct,
                                               const float* __restrict__ bfc,
                                               float* __restrict__ out, int N) {
    __shared__ unsigned short h2s[64 * 136];
    const int tid = threadIdx.x;
    const int wv = tid >> 6, lane = tid & 63;
    const int grp = lane >> 3, l8 = lane & 7;   // 8 groups x 8 lanes
    const int nbase = blockIdx.x * 64;

    // ---- gather phase: wave wv fills rows wv*16 .. wv*16+15 ----
    for (int p = 0; p < 2; p++) {
        int r = wv * 16 + p * 8 + grp;
        int node = nbase + r;
        float acc[16];
#pragma unroll
        for (int k = 0; k < 16; k++) acc[k] = 0.f;
        float d = 0.f;
        if (node < N) {
            d = dis[node];
            float vs = hscale[node];           // self term, weight 1
            float vsum = vs;
            uint4 s0 = h8[(size_t)node * 8 + l8];
            fma16_u8(acc, vs, s0);
            int j = rowptr[node], jend = rowptr[node + 1];
            for (; j < jend; j++) {
                uint2 m = meta[j];
                float v = __uint_as_float(m.y) * hscale[m.x];
                uint4 g = h8[(size_t)m.x * 8 + l8];
                vsum += v;
                fma16_u8(acc, v, g);
            }
            float b128 = 128.f * vsum;
#pragma unroll
            for (int k = 0; k < 16; k++) acc[k] -= b128;
        }
        // bias + relu + scale; lane covers cols l8*16 .. l8*16+15
        unsigned int wpk[8];
#pragma unroll
        for (int q = 0; q < 4; q++) {
            float4 bv = ((const float4*)b2)[l8 * 4 + q];
            float a0 = fmaxf(fmaf(d, acc[q * 4 + 0], bv.x), 0.f);
            float a1 = fmaxf(fmaf(d, acc[q * 4 + 1], bv.y), 0.f);
            float a2 = fmaxf(fmaf(d, acc[q * 4 + 2], bv.z), 0.f);
            float a3 = fmaxf(fmaf(d, acc[q * 4 + 3], bv.w), 0.f);
            if (node >= N) { a0 = a1 = a2 = a3 = 0.f; }
            wpk[q * 2]     = packh(a0, a1);
            wpk[q * 2 + 1] = packh(a2, a3);
        }
        *(uint4*)&h2s[r * 136 + l8 * 16] =
            make_uint4(wpk[0], wpk[1], wpk[2], wpk[3]);
        *(uint4*)&h2s[r * 136 + l8 * 16 + 8] =
            make_uint4(wpk[4], wpk[5], wpk[6], wpk[7]);
    }
    // no __syncthreads(): each wave reads back only the rows it wrote

    // ---- fc phase: wave wv handles its rows wv*16..+15 ----
    const int q = lane >> 4, m = lane & 15;
    f16x8 af[4];
#pragma unroll
    for (int ks = 0; ks < 4; ks++)
        af[ks] = *(const f16x8*)&h2s[(wv * 16 + m) * 136 + ks * 32 + q * 8];

#pragma unroll
    for (int n = 0; n < 2; n++) {
        f32x4 o = (f32x4)0.f;
#pragma unroll
        for (int ks = 0; ks < 4; ks++) {
            f16x8 bfr = *(const f16x8*)&wfct[(size_t)(n * 16 + m) * 128 + ks * 32 + q * 8];
            o = __builtin_amdgcn_mfma_f32_16x16x32_f16(af[ks], bfr, o, 0, 0, 0);
        }
        int col = n * 16 + m;
        if (col < NCLASS) {
            float bv = bfc[col];
            int r0 = nbase + wv * 16 + q * 4;
#pragma unroll
            for (int r = 0; r < 4; r++) {
                if (r0 + r < N)
                    out[(size_t)(r0 + r) * NCLASS + col] = o[r] + bv;
            }
        }
    }
}

extern "C" void kernel_launch(void* const* d_in, const int* in_sizes, int n_in,
                              void* d_out, int out_size, void* d_ws, size_t ws_size,
                              hipStream_t stream) {
    const float* x   = (const float*)d_in[0];
    const int*   ei  = (const int*)d_in[1];
    const float* ew  = (const float*)d_in[2];
    const float* W1  = (const float*)d_in[3];
    const float* b1  = (const float*)d_in[4];
    const float* W2  = (const float*)d_in[5];
    const float* b2  = (const float*)d_in[6];
    const float* Wfc = (const float*)d_in[7];
    const float* bfc = (const float*)d_in[8];
    float* out = (float*)d_out;

    const int N = NNODES;
    const int* erow = ei;
    const int* ecol = ei + NEDGES;

    // ws layout (float-unit offsets):
    float* fws    = (float*)d_ws;
    float* dis    = fws;                                       // 100000
    int*   rowptr = (int*)(fws + 100000);                      // 100001 (+pad)
    int*   H      = (int*)(fws + 200004);                      // 114856
    int*   incl   = (int*)(fws + 314860);                      // 114856
    int*   aux    = (int*)(fws + 429716);                      // 512
    uint2* rw     = (uint2*)(fws + 430228);                    // 600000 uint2
    unsigned short* lc = (unsigned short*)(fws + 1630228);     // 600000 u16
    uint2* meta   = (uint2*)(fws + 1930228);                   // 600000 uint2
    unsigned short* wt16   = (unsigned short*)(fws + 3130228); // 128*128
    unsigned short* w1t16  = (unsigned short*)(fws + 3138420); // 128*32
    unsigned short* wfct16 = (unsigned short*)(fws + 3140468); // 32*128
    unsigned int*   xq     = (unsigned int*)(fws + 3142516);   // N*8 uints (int8 xs)
    float*          xscale = (float*)(fws + 3942516);          // N per-row scales
    unsigned char*  hB8    = (unsigned char*)(fws + 6342516);  // N*128 u8 (biased int8)
    float*          hscale = (float*)(fws + 9542516);          // N per-row scales

    const int gScan = (NH + 255) / 256;   // 449
    const int gPrep = 96 + (N * 8 + 255) / 256;
    const int g64   = (N + 63) / 64;      // 1563

    // ---- CSR build (5 kernels) ----
    histA_k<<<NBE, 256, 0, stream>>>(ecol, H);
    scanH1_k<<<gScan, 256, 0, stream>>>(H, incl, aux, NH);
    scan2_k<<<1, 512, 0, stream>>>(aux, gScan);
    partB_k<<<NBE, 256, 0, stream>>>(erow, ecol, ew, incl, H, aux, rw, lc);
    segbp_k<<<NBKT, 256, 0, stream>>>(rw, lc, incl, H, aux, rowptr, dis, meta);

    // ---- prep (weights + int8 xs + scales, full-device parallelism) ----
    prep_k<<<gPrep, 256, 0, stream>>>(W2, W1, Wfc, x, dis, wt16, w1t16, wfct16,
                                      xq, xscale);

    // ---- fused layer-1 agg (int8, L2-resident) + gemm1 + gemm2 ----
    agggemm_k<<<g64, 256, 0, stream>>>(rowptr, meta, (const uint2*)xq, xscale,
                                       w1t16, b1, wt16, dis, hB8, hscale, N);

    // ---- fused agg128 + fc (biased-int8 gather) ----
    aggfc_k<<<g64, 256, 0, stream>>>(rowptr, meta, (const uint4*)hB8, hscale, dis, b2,
                                     wfct16, bfc, out, N);
}